// Round 1
// baseline (4244.374 us; speedup 1.0000x reference)
//
#include <hip/hip_runtime.h>

// Elman ReLU RNN, fully fused persistent kernel, barrier-amortized version.
// B=256 blocks (1 batch per CU), 192 threads (3 waves):
//   wave 0: THE recurrence wave. Computes ALL 116 h-elements per step
//           (lane l < 58 owns rows 2l, 2l+1; W_hh fully in VGPRs, ~232 regs).
//           Its step-to-step dependency (write h -> lgkmcnt -> broadcast read)
//           is wave-private: NO barrier on the serial critical path.
//   wave 1: fc output, lagging ONE superstep (reads h[u], u in [8s-9, 8s-2]),
//           so every h it reads is already barrier-published.
//   wave 2: xp producer, leading ONE superstep (writes xp[tau], tau in
//           [8s+8, 8s+15]), plus private x ring (global -> reg -> LDS).
// Barrier fires once per superstep (8 steps): 256+2 barriers vs 2048 before.
// Ring depths: h 32 (writer [8s,8s+7] vs reader [8s-9,8s-2] mod 32: disjoint),
// xp 16 (writer [8s+8,8s+15] vs reader [8s,8s+7] mod 16: disjoint halves).

namespace {
constexpr int kB = 256;
constexpr int kT = 2048;
constexpr int kI = 50;
constexpr int kH = 116;
constexpr int kO = 50;
constexpr int kK = 8;     // steps per superstep (barrier period)
constexpr int kHD = 32;   // h ring depth
constexpr int kXPD = 16;  // xp ring depth
}

struct Smem {
  alignas(16) float h[kHD][128];    // h ring, slot t & 31
  alignas(16) float xp[kXPD][128];  // xp ring, slot t & 15
  alignas(16) float xr[4][52];      // x ring (wave-2 private), slot t & 3
};

__device__ __forceinline__ void sync_lds() {
  // Drain LDS only; vmcnt stays in flight (x prefetch + out stores pipeline).
  __asm__ __volatile__("s_waitcnt lgkmcnt(0)\n\ts_barrier" ::: "memory");
}

// One recurrence step, single wave, lane l < 58 produces h[2l], h[2l+1].
// Accumulator structure matches the previous kernel exactly (4 chains per
// output, a0 seeded with xp) so the h trajectory is bitwise identical.
__device__ __forceinline__ void h_step(Smem& sm, int t, const float (&w0)[kH],
                                       const float (&w1)[kH], int l) {
  const float4* hp = (const float4*)sm.h[(t + kHD - 1) & (kHD - 1)];
  const float2 xp2 = *(const float2*)&sm.xp[t & (kXPD - 1)][2 * l];
  float a00 = xp2.x, a01 = 0.f, a02 = 0.f, a03 = 0.f;
  float a10 = xp2.y, a11 = 0.f, a12 = 0.f, a13 = 0.f;
#pragma unroll
  for (int i = 0; i < kH / 4; ++i) {
    float4 v = hp[i];
    a00 = fmaf(w0[4 * i + 0], v.x, a00);
    a01 = fmaf(w0[4 * i + 1], v.y, a01);
    a02 = fmaf(w0[4 * i + 2], v.z, a02);
    a03 = fmaf(w0[4 * i + 3], v.w, a03);
    a10 = fmaf(w1[4 * i + 0], v.x, a10);
    a11 = fmaf(w1[4 * i + 1], v.y, a11);
    a12 = fmaf(w1[4 * i + 2], v.z, a12);
    a13 = fmaf(w1[4 * i + 3], v.w, a13);
  }
  float h0 = (a00 + a01) + (a02 + a03);
  float h1 = (a10 + a11) + (a12 + a13);
  *(float2*)&sm.h[t & (kHD - 1)][2 * l] =
      make_float2(h0 > 0.f ? h0 : 0.f, h1 > 0.f ? h1 : 0.f);
}

__device__ __forceinline__ void fc_step(Smem& sm, int u, const float (&wrow)[kH],
                                        float bfc, float* __restrict__ ob,
                                        int ln) {
  const float4* hp = (const float4*)sm.h[u & (kHD - 1)];
  float a0 = bfc, a1 = 0.f, a2 = 0.f, a3 = 0.f;
#pragma unroll
  for (int i = 0; i < kH / 4; ++i) {
    float4 v = hp[i];
    a0 = fmaf(wrow[4 * i + 0], v.x, a0);
    a1 = fmaf(wrow[4 * i + 1], v.y, a1);
    a2 = fmaf(wrow[4 * i + 2], v.z, a2);
    a3 = fmaf(wrow[4 * i + 3], v.w, a3);
  }
  ob[(size_t)u * kO + ln] = (a0 + a1) + (a2 + a3);
}

__device__ __forceinline__ void xp_step(Smem& sm, int xs, int slot,
                                        const float (&wi0)[kI],
                                        const float (&wi1)[kI],
                                        float bias0, float bias1, int ln) {
  const float4* xq = (const float4*)sm.xr[xs];
  float s00 = 0.f, s01 = 0.f, s02 = 0.f, s03 = 0.f;
  float s10 = 0.f, s11 = 0.f, s12 = 0.f, s13 = 0.f;
#pragma unroll
  for (int i = 0; i < 12; ++i) {
    float4 v = xq[i];
    s00 = fmaf(wi0[4 * i + 0], v.x, s00);
    s01 = fmaf(wi0[4 * i + 1], v.y, s01);
    s02 = fmaf(wi0[4 * i + 2], v.z, s02);
    s03 = fmaf(wi0[4 * i + 3], v.w, s03);
    s10 = fmaf(wi1[4 * i + 0], v.x, s10);
    s11 = fmaf(wi1[4 * i + 1], v.y, s11);
    s12 = fmaf(wi1[4 * i + 2], v.z, s12);
    s13 = fmaf(wi1[4 * i + 3], v.w, s13);
  }
  float2 vt = ((const float2*)sm.xr[xs])[24];  // elements 48,49
  s00 = fmaf(wi0[48], vt.x, s00);
  s01 = fmaf(wi0[49], vt.y, s01);
  s10 = fmaf(wi1[48], vt.x, s10);
  s11 = fmaf(wi1[49], vt.y, s11);
  sm.xp[slot][ln] = bias0 + ((s00 + s01) + (s02 + s03));
  if (ln < kH - 64) sm.xp[slot][ln + 64] = bias1 + ((s10 + s11) + (s12 + s13));
}

__launch_bounds__(192, 1)
__global__ void rnn_fused(const float* __restrict__ x,
                          const float* __restrict__ W_ih,
                          const float* __restrict__ b_ih,
                          const float* __restrict__ W_hh,
                          const float* __restrict__ b_hh,
                          const float* __restrict__ W_fc,
                          const float* __restrict__ b_fc,
                          float* __restrict__ out) {
  __shared__ Smem sm;
  const int tid = threadIdx.x;
  const int wv = tid >> 6;
  const int ln = tid & 63;
  const int b = blockIdx.x;
  const float* xb = x + (size_t)b * (kT * kI);
  float* ob = out + (size_t)b * (kT * kO);

  float w0[kH], w1[kH];    // wave 0: W_hh rows 2l, 2l+1; wave 1: w0 = W_fc row
  float wi0[kI], wi1[kI];  // wave 2: W_ih rows ln, ln+64
  float bias0 = 0.f, bias1 = 0.f, bfc = 0.f;
  float xrv[4] = {0.f, 0.f, 0.f, 0.f};  // x prefetch regs, xrv[k] -> ring slot k

  if (wv == 0) {
    if (ln < kH / 2) {
      const float4* r0 = (const float4*)(W_hh + (2 * ln) * kH);      // 464B rows
      const float4* r1 = (const float4*)(W_hh + (2 * ln + 1) * kH);  // 16B aligned
#pragma unroll
      for (int i = 0; i < kH / 4; ++i) {
        float4 v = r0[i];
        w0[4 * i + 0] = v.x; w0[4 * i + 1] = v.y;
        w0[4 * i + 2] = v.z; w0[4 * i + 3] = v.w;
        float4 u = r1[i];
        w1[4 * i + 0] = u.x; w1[4 * i + 1] = u.y;
        w1[4 * i + 2] = u.z; w1[4 * i + 3] = u.w;
      }
      // h[-1] = 0 lives at slot (0-1) & 31 = 31
      *(float2*)&sm.h[kHD - 1][2 * ln] = make_float2(0.f, 0.f);
    }
  } else if (wv == 1) {
    if (ln < kO) {
      const float4* wr = (const float4*)(W_fc + ln * kH);
#pragma unroll
      for (int i = 0; i < kH / 4; ++i) {
        float4 v = wr[i];
        w0[4 * i + 0] = v.x; w0[4 * i + 1] = v.y;
        w0[4 * i + 2] = v.z; w0[4 * i + 3] = v.w;
      }
      bfc = b_fc[ln];
    }
  } else {
    {
      const float2* wr = (const float2*)(W_ih + ln * kI);  // 200B rows: 8B aligned
#pragma unroll
      for (int i = 0; i < kI / 2; ++i) {
        float2 v = wr[i]; wi0[2 * i] = v.x; wi0[2 * i + 1] = v.y;
      }
      bias0 = b_ih[ln] + b_hh[ln];
    }
    if (ln < kH - 64) {
      const float2* wr = (const float2*)(W_ih + (ln + 64) * kI);
#pragma unroll
      for (int i = 0; i < kI / 2; ++i) {
        float2 v = wr[i]; wi1[2 * i] = v.x; wi1[2 * i + 1] = v.y;
      }
      bias1 = b_ih[ln + 64] + b_hh[ln + 64];
    } else {
#pragma unroll
      for (int i = 0; i < kI; ++i) wi1[i] = 0.f;
    }
    if (ln < kI) {
      // Ring invariant at step tau: slots tau&3, (tau+1)&3 hold x[tau], x[tau+1];
      // xrv[k] holds the x destined for slot k (x index = next with idx&3 == k).
      sm.xr[0][ln] = xb[0 * kI + ln];
      sm.xr[1][ln] = xb[1 * kI + ln];
      xrv[2] = xb[2 * kI + ln];
      xrv[3] = xb[3 * kI + ln];
      xrv[0] = xb[4 * kI + ln];
      xrv[1] = xb[5 * kI + ln];
    }
  }
  sync_lds();  // barrier 0: init published

  // Give the serial recurrence wave scheduler priority (LDS/issue arbitration).
  if (wv == 0) __builtin_amdgcn_s_setprio(1);

  // xp prologue: tau = 0..7 fills xp slots 0..7 so wave 0 can start at t=0.
  if (wv == 2) {
#pragma unroll 4
    for (int j = 0; j < kK; ++j) {
      xp_step(sm, j & 3, j & (kXPD - 1), wi0, wi1, bias0, bias1, ln);
      if (ln < kI) {
        const int ws = (j + 2) & 3;
        sm.xr[ws][ln] = xrv[ws];
        const int tf = j + 6;  // <= 13, no clamp needed
        xrv[ws] = xb[(size_t)tf * kI + ln];
      }
    }
  }
  sync_lds();  // barrier 1: xp[0..7] published

#pragma unroll 1
  for (int s = 0; s < kT / kK; ++s) {
    if (wv == 0) {
      // 8 serial steps, no barrier inside: write->lgkmcnt->read is in-wave.
      if (ln < kH / 2) {
#pragma unroll 2
        for (int j = 0; j < kK; ++j) h_step(sm, kK * s + j, w0, w1, ln);
      }
    } else if (wv == 1) {
      // Lag one superstep: u in [8s-9, 8s-2]; all h[u] barrier-published.
      if (ln < kO && s > 0) {
        const int u0 = kK * s - (kK + 1);
#pragma unroll 2
        for (int j = 0; j < kK; ++j) {
          const int u = u0 + j;
          if (u >= 0) fc_step(sm, u, w0, bfc, ob, ln);
        }
      }
    } else {
      // Lead one superstep: tau in [8s+8, 8s+15]; slot halves disjoint from
      // wave 0's reads this superstep.
      if (s < kT / kK - 1) {
        const int tau0 = kK * s + kK;
#pragma unroll 4
        for (int j = 0; j < kK; ++j) {
          const int tau = tau0 + j;
          xp_step(sm, j & 3, tau & (kXPD - 1), wi0, wi1, bias0, bias1, ln);
          if (ln < kI) {
            const int ws = (j + 2) & 3;
            sm.xr[ws][ln] = xrv[ws];
            int tf = tau + 6; tf = tf < kT ? tf : kT - 1;
            xrv[ws] = xb[(size_t)tf * kI + ln];
          }
        }
      }
    }
    sync_lds();  // one barrier per 8 steps
  }

  // fc epilogue: u = 2039..2047 (all h published by the final barrier).
  if (wv == 1 && ln < kO) {
#pragma unroll 1
    for (int u = kT - (kK + 1); u < kT; ++u) fc_step(sm, u, w0, bfc, ob, ln);
  }
}

extern "C" void kernel_launch(void* const* d_in, const int* in_sizes, int n_in,
                              void* d_out, int out_size, void* d_ws, size_t ws_size,
                              hipStream_t stream) {
  (void)in_sizes; (void)n_in; (void)d_ws; (void)ws_size; (void)out_size;
  const float* x    = (const float*)d_in[0];
  const float* W_ih = (const float*)d_in[1];
  const float* b_ih = (const float*)d_in[2];
  const float* W_hh = (const float*)d_in[3];
  const float* b_hh = (const float*)d_in[4];
  const float* W_fc = (const float*)d_in[5];
  const float* b_fc = (const float*)d_in[6];
  float* out = (float*)d_out;
  rnn_fused<<<dim3(kB), dim3(192), 0, stream>>>(x, W_ih, b_ih, W_hh, b_hh,
                                                W_fc, b_fc, out);
}

// Round 3
// 1208.624 us; speedup vs baseline: 3.5117x; 3.5117x over previous
//
#include <hip/hip_runtime.h>

// Elman ReLU RNN, fused persistent kernel. Round-0 skeleton (4 waves, one
// lgkm-only barrier per step) + split-K-4 matvecs to kill LDS broadcast
// bandwidth (the measured per-step bottleneck).
//
// B=256 blocks (1 batch per CU), 256 threads (4 waves):
//   waves 0-1: h-update. Lane l: chunk k = l&3 (h elements [32k,32k+32)),
//              rows rloc + 16p (rloc = l>>2, p = 0..3), rows offset by 58*wv.
//              Weights W_hh[4 rows][32 cols] in 128 VGPRs. Per step: 8
//              ds_read_b128 (own chunk only, vs 29 broadcast before), 128
//              FMAs, quad-reduce via DPP (VALU-only), one b32 write.
//   wave  2  : fc for h[t-1], same split-K-4 structure over 50 output rows.
//   wave  3  : xp[t+1] = W_ih x[t+1] + b_ih + b_hh (rows ln, ln+64 in VGPRs)
//              + x streaming: global -> 4-deep reg ring -> LDS ring.
// h is stored chunk-padded (36 floats per 32-chunk) so the 4 distinct chunk
// addresses inside one ds_read_b128 hit disjoint bank groups (no conflicts).

namespace {
constexpr int kB = 256;
constexpr int kT = 2048;
constexpr int kI = 50;
constexpr int kH = 116;
constexpr int kO = 50;
}

struct Smem {
  // h element e lives at float index 36*(e>>5) + (e&31); chunk k = float4 idx 9k.
  alignas(16) float h[2][144];    // double buffer, parity t&1, padded layout
  alignas(16) float xp[2][128];   // xp double buffer, parity t&1 (plain layout)
  alignas(16) float xr[4][52];    // x ring, slot t&3 (52: pad to 13 float4)
};

__device__ __forceinline__ void sync_lds() {
  // Workgroup barrier draining LDS only; vmcnt stays in flight so the global
  // x prefetch and fc output stores pipeline across steps.
  __asm__ __volatile__("s_waitcnt lgkmcnt(0)\n\ts_barrier" ::: "memory");
}

// Quad butterfly adds via DPP quad_perm: VALU-only, no LDS pipe traffic.
__device__ __forceinline__ float qadd1(float v) {  // + lane^1
  return v + __int_as_float(__builtin_amdgcn_update_dpp(
                 0, __float_as_int(v), 0xB1, 0xF, 0xF, true));
}
__device__ __forceinline__ float qadd2(float v) {  // + lane^2
  return v + __int_as_float(__builtin_amdgcn_update_dpp(
                 0, __float_as_int(v), 0x4E, 0xF, 0xF, true));
}

// h-update step: lane contributes chunk k to rows rloc + 16p; keeps row
// rowk = rbase + rl + 16k after the quad reduce. hwr = padded write index.
__device__ __forceinline__ void h_step(Smem& sm, int pw, int pr,
                                       const float (&w)[4][32], int k,
                                       int rowk, int hwr, bool wvalid) {
  const float xpv = sm.xp[pw][rowk];
  const float4* hp4 = (const float4*)sm.h[pr];
  float4 hc[8];
#pragma unroll
  for (int i = 0; i < 8; ++i) hc[i] = hp4[9 * k + i];
  float res = 0.f;
#pragma unroll
  for (int p = 0; p < 4; ++p) {
    float s0 = 0.f, s1 = 0.f, s2 = 0.f, s3 = 0.f;
#pragma unroll
    for (int i = 0; i < 8; ++i) {
      const float4 v = hc[i];
      s0 = fmaf(w[p][4 * i + 0], v.x, s0);
      s1 = fmaf(w[p][4 * i + 1], v.y, s1);
      s2 = fmaf(w[p][4 * i + 2], v.z, s2);
      s3 = fmaf(w[p][4 * i + 3], v.w, s3);
    }
    float c = (s0 + s1) + (s2 + s3);
    c = qadd2(qadd1(c));  // quad total, bit-identical in all 4 lanes
    res = (k == p) ? c : res;
  }
  res += xpv;
  res = res > 0.f ? res : 0.f;
  if (wvalid) sm.h[pw][hwr] = res;
}

// fc step for h[u] (ring slot = u&1): same split-K-4 shape, global store.
__device__ __forceinline__ void fc_step(Smem& sm, int slot,
                                        const float (&w)[4][32], int k,
                                        int rowk, float bfc,
                                        float* __restrict__ ob, size_t ubase) {
  const float4* hp4 = (const float4*)sm.h[slot];
  float4 hc[8];
#pragma unroll
  for (int i = 0; i < 8; ++i) hc[i] = hp4[9 * k + i];
  float res = 0.f;
#pragma unroll
  for (int p = 0; p < 4; ++p) {
    float s0 = 0.f, s1 = 0.f, s2 = 0.f, s3 = 0.f;
#pragma unroll
    for (int i = 0; i < 8; ++i) {
      const float4 v = hc[i];
      s0 = fmaf(w[p][4 * i + 0], v.x, s0);
      s1 = fmaf(w[p][4 * i + 1], v.y, s1);
      s2 = fmaf(w[p][4 * i + 2], v.z, s2);
      s3 = fmaf(w[p][4 * i + 3], v.w, s3);
    }
    float c = (s0 + s1) + (s2 + s3);
    c = qadd2(qadd1(c));
    res = (k == p) ? c : res;
  }
  res += bfc;
  if (rowk < kO) ob[ubase + rowk] = res;
}

__device__ __forceinline__ void xp_step(Smem& sm, int xs, int xpp,
                                        const float (&wi0)[kI],
                                        const float (&wi1)[kI],
                                        float bias0, float bias1, int ln) {
  const float4* xq = (const float4*)sm.xr[xs];
  float s00 = 0.f, s01 = 0.f, s02 = 0.f, s03 = 0.f;
  float s10 = 0.f, s11 = 0.f, s12 = 0.f, s13 = 0.f;
#pragma unroll
  for (int i = 0; i < 12; ++i) {
    float4 v = xq[i];
    s00 = fmaf(wi0[4 * i + 0], v.x, s00);
    s01 = fmaf(wi0[4 * i + 1], v.y, s01);
    s02 = fmaf(wi0[4 * i + 2], v.z, s02);
    s03 = fmaf(wi0[4 * i + 3], v.w, s03);
    s10 = fmaf(wi1[4 * i + 0], v.x, s10);
    s11 = fmaf(wi1[4 * i + 1], v.y, s11);
    s12 = fmaf(wi1[4 * i + 2], v.z, s12);
    s13 = fmaf(wi1[4 * i + 3], v.w, s13);
  }
  float2 vt = ((const float2*)sm.xr[xs])[24];  // elements 48,49
  s00 = fmaf(wi0[48], vt.x, s00);
  s01 = fmaf(wi0[49], vt.y, s01);
  s10 = fmaf(wi1[48], vt.x, s10);
  s11 = fmaf(wi1[49], vt.y, s11);
  sm.xp[xpp][ln] = bias0 + ((s00 + s01) + (s02 + s03));
  if (ln < kH - 64) sm.xp[xpp][ln + 64] = bias1 + ((s10 + s11) + (s12 + s13));
}

__launch_bounds__(256, 1)
__global__ void rnn_fused(const float* __restrict__ x,
                          const float* __restrict__ W_ih,
                          const float* __restrict__ b_ih,
                          const float* __restrict__ W_hh,
                          const float* __restrict__ b_hh,
                          const float* __restrict__ W_fc,
                          const float* __restrict__ b_fc,
                          float* __restrict__ out) {
  __shared__ Smem sm;
  const int tid = threadIdx.x;
  const int wv = tid >> 6;
  const int ln = tid & 63;
  const int b = blockIdx.x;
  const float* xb = x + (size_t)b * (kT * kI);
  float* ob = out + (size_t)b * (kT * kO);

  float w[4][32];          // waves 0-2: per-lane weight tile (chunk k, 4 rows)
  float wi0[kI], wi1[kI];  // wave 3: W_ih rows ln, ln+64
  float bias0 = 0.f, bias1 = 0.f, bfc = 0.f;
  float xr0 = 0.f, xr1 = 0.f, xr2 = 0.f, xr3 = 0.f;  // x prefetch regs, by slot

  const int k = ln & 3;    // K-chunk (h columns [32k, 32k+32))
  const int rl = ln >> 2;  // local row 0..15
  int rowk = 0, hwr = 0;   // kept row after quad reduce; padded write index
  bool wvalid = false;

  if (wv < 2) {
    const int rbase = 58 * wv;
    rowk = rbase + rl + 16 * k;
    wvalid = (rl + 16 * k) < 58;
    hwr = 36 * (rowk >> 5) + (rowk & 31);
#pragma unroll
    for (int p = 0; p < 4; ++p) {
      const int rloc = rl + 16 * p;
      const bool vr = rloc < 58;
      const size_t r = rbase + (vr ? rloc : 0);
#pragma unroll
      for (int j = 0; j < 32; ++j) {
        const int col = 32 * k + j;
        w[p][j] = (vr && col < kH) ? W_hh[r * kH + col] : 0.f;
      }
    }
  } else if (wv == 2) {
    rowk = rl + 16 * k;
#pragma unroll
    for (int p = 0; p < 4; ++p) {
      const int rloc = rl + 16 * p;
      const bool vr = rloc < kO;
      const size_t r = vr ? rloc : 0;
#pragma unroll
      for (int j = 0; j < 32; ++j) {
        const int col = 32 * k + j;
        w[p][j] = (vr && col < kH) ? W_fc[r * kH + col] : 0.f;
      }
    }
    bfc = (rowk < kO) ? b_fc[rowk] : 0.f;
  } else {
    {
      const float2* wr = (const float2*)(W_ih + ln * kI);  // 200B rows: 8B aligned
#pragma unroll
      for (int i = 0; i < kI / 2; ++i) {
        float2 v = wr[i]; wi0[2 * i] = v.x; wi0[2 * i + 1] = v.y;
      }
      bias0 = b_ih[ln] + b_hh[ln];
    }
    if (ln < kH - 64) {
      const float2* wr = (const float2*)(W_ih + (ln + 64) * kI);
#pragma unroll
      for (int i = 0; i < kI / 2; ++i) {
        float2 v = wr[i]; wi1[2 * i] = v.x; wi1[2 * i + 1] = v.y;
      }
      bias1 = b_ih[ln + 64] + b_hh[ln + 64];
    } else {
#pragma unroll
      for (int i = 0; i < kI; ++i) wi1[i] = 0.f;
    }
    if (ln < kI) {
      sm.xr[0][ln] = xb[0 * kI + ln];
      sm.xr[1][ln] = xb[1 * kI + ln];
      xr2 = xb[2 * kI + ln];
      xr3 = xb[3 * kI + ln];
      xr0 = xb[4 * kI + ln];
      xr1 = xb[5 * kI + ln];
    }
  }
  // Zero both h buffers entirely (h[-1] = 0 at parity 1; padded tails stay 0).
  if (tid < 144) { sm.h[0][tid] = 0.f; sm.h[1][tid] = 0.f; }
  sync_lds();

  if (wv == 3) xp_step(sm, /*xs=*/0, /*xpp=*/0, wi0, wi1, bias0, bias1, ln);
  sync_lds();

  // Per step t: h waves read sm.xp[t&1] and sm.h[(t-1)&1], write sm.h[t&1];
  // fc reads sm.h[(t-1)&1] -> out[t-1]; wave 3 writes sm.xp[(t+1)&1] from
  // sm.xr[(t+1)&3], refills sm.xr[(t+2)&3], prefetches x[t+6].
#define RNN_STEP(T_, XRV)                                                   \
  {                                                                         \
    const int t = (T_);                                                     \
    const int pw = t & 1, pr = (t + 1) & 1;                                 \
    if (wv < 2) {                                                           \
      h_step(sm, pw, pr, w, k, rowk, hwr, wvalid);                          \
    } else if (wv == 2) {                                                   \
      if (t > 0) fc_step(sm, pr, w, k, rowk, bfc, ob, (size_t)(t - 1) * kO);\
    } else {                                                                \
      xp_step(sm, (t + 1) & 3, (t + 1) & 1, wi0, wi1, bias0, bias1, ln);    \
      if (ln < kI) {                                                        \
        sm.xr[(t + 2) & 3][ln] = (XRV);                                     \
        int tf = t + 6; tf = tf < kT ? tf : kT - 1;                         \
        (XRV) = xb[(size_t)tf * kI + ln];                                   \
      }                                                                     \
    }                                                                       \
    sync_lds();                                                             \
  }

  for (int t0 = 0; t0 < kT; t0 += 4) {
    RNN_STEP(t0 + 0, xr2)
    RNN_STEP(t0 + 1, xr3)
    RNN_STEP(t0 + 2, xr0)
    RNN_STEP(t0 + 3, xr1)
  }
#undef RNN_STEP

  // fc for the final step's h (parity (T-1)&1 = 1)
  if (wv == 2) fc_step(sm, (kT - 1) & 1, w, k, rowk, bfc, ob,
                       (size_t)(kT - 1) * kO);
}

extern "C" void kernel_launch(void* const* d_in, const int* in_sizes, int n_in,
                              void* d_out, int out_size, void* d_ws, size_t ws_size,
                              hipStream_t stream) {
  (void)in_sizes; (void)n_in; (void)d_ws; (void)ws_size; (void)out_size;
  const float* x    = (const float*)d_in[0];
  const float* W_ih = (const float*)d_in[1];
  const float* b_ih = (const float*)d_in[2];
  const float* W_hh = (const float*)d_in[3];
  const float* b_hh = (const float*)d_in[4];
  const float* W_fc = (const float*)d_in[5];
  const float* b_fc = (const float*)d_in[6];
  float* out = (float*)d_out;
  rnn_fused<<<dim3(kB), dim3(256), 0, stream>>>(x, W_ih, b_ih, W_hh, b_hh,
                                                W_fc, b_fc, out);
}

// Round 4
// 1055.638 us; speedup vs baseline: 4.0207x; 1.1449x over previous
//
#include <hip/hip_runtime.h>

// Elman ReLU RNN, fused persistent kernel. Round-3 split-K-4 math (proven,
// 156 VGPR) + flag-based h-wave handshake replacing the per-step barrier.
//
// B=256 blocks (1 batch per CU), 256 threads (4 waves):
//   waves 0-1: h-update, split-K-4 (lane: chunk k=l&3, rows rl+16p, offset
//              58*wv). Per step: poll OTHER h-wave's flag >= t-1 (LDS flag,
//              monotonic), read h(t-1) + xp[t], compute, write h(t), bump own
//              flag. NO workgroup barrier on the serial path.
//   wave  2  : fc, lagging one superstep (u in [8s-8, 8s-1], barrier-published).
//   wave  3  : xp producer, leading one superstep (tau in [8s+8, 8s+15]),
//              + x streaming: global -> 4-deep reg ring -> LDS ring.
// Full (lgkm-only) barrier once per 8 steps: 258 barriers vs 2048.
// Rings: h depth 16 (h-wave skew <=1 by poll; fc lag <=8: writer slots
// [8s..8s+7] vs fc reads [8s-8..8s-1] mod 16 disjoint), xp depth 16 (writer
// [8s+8..8s+15] vs h reads [8s..8s+7] mod 16 disjoint).

namespace {
constexpr int kB = 256;
constexpr int kT = 2048;
constexpr int kI = 50;
constexpr int kH = 116;
constexpr int kO = 50;
constexpr int kSS = 8;    // steps per superstep (barrier period)
constexpr int kHD = 16;   // h ring depth
constexpr int kXPD = 16;  // xp ring depth
}

struct Smem {
  // h element e of step t lives at h[t&15][36*(e>>5) + (e&31)] (chunk-padded:
  // chunk k = float4 index 9k, so the 4 distinct chunk addresses in one
  // ds_read_b128 hit disjoint bank groups).
  alignas(16) float h[kHD][144];    // 9216 B
  alignas(16) float xp[kXPD][128];  // 8192 B
  alignas(16) float xr[4][52];      // x ring, slot tau&3 (wave-3 private)
  int flags[2];                     // per-h-wave completed-step counters
};

__device__ __forceinline__ void sync_lds() {
  // Workgroup barrier draining LDS only; vmcnt stays in flight so the global
  // x prefetch and fc output stores pipeline across supersteps.
  __asm__ __volatile__("s_waitcnt lgkmcnt(0)\n\ts_barrier" ::: "memory");
}

__device__ __forceinline__ void wait_flag(const volatile int* f, int want) {
  // Spin until the other h-wave's completed-step counter reaches `want`.
  // volatile forces a ds_read per iteration; readfirstlane scalarizes the
  // loop condition. The trailing memory clobber stops the compiler from
  // hoisting the subsequent h-ring ds_reads above the poll.
  while (__builtin_amdgcn_readfirstlane(*f) < want) {}
  __asm__ __volatile__("" ::: "memory");
}

// Quad butterfly adds via DPP quad_perm: VALU-only, no LDS pipe traffic.
__device__ __forceinline__ float qadd1(float v) {  // + lane^1
  return v + __int_as_float(__builtin_amdgcn_update_dpp(
                 0, __float_as_int(v), 0xB1, 0xF, 0xF, true));
}
__device__ __forceinline__ float qadd2(float v) {  // + lane^2
  return v + __int_as_float(__builtin_amdgcn_update_dpp(
                 0, __float_as_int(v), 0x4E, 0xF, 0xF, true));
}

// h-update step t: reads xp[t&15], h[(t-1)&15]; writes h[t&15].
// Arithmetic identical to the round-3 kernel (bit-identical trajectory).
__device__ __forceinline__ void h_step(Smem& sm, int t, const float (&w)[4][32],
                                       int k, int rowk, int hwr, bool wvalid) {
  const float xpv = sm.xp[t & (kXPD - 1)][rowk];
  const float4* hp4 = (const float4*)sm.h[(t + kHD - 1) & (kHD - 1)];
  float4 hc[8];
#pragma unroll
  for (int i = 0; i < 8; ++i) hc[i] = hp4[9 * k + i];
  float res = 0.f;
#pragma unroll
  for (int p = 0; p < 4; ++p) {
    float s0 = 0.f, s1 = 0.f, s2 = 0.f, s3 = 0.f;
#pragma unroll
    for (int i = 0; i < 8; ++i) {
      const float4 v = hc[i];
      s0 = fmaf(w[p][4 * i + 0], v.x, s0);
      s1 = fmaf(w[p][4 * i + 1], v.y, s1);
      s2 = fmaf(w[p][4 * i + 2], v.z, s2);
      s3 = fmaf(w[p][4 * i + 3], v.w, s3);
    }
    float c = (s0 + s1) + (s2 + s3);
    c = qadd2(qadd1(c));  // quad total, bit-identical in all 4 lanes
    res = (k == p) ? c : res;
  }
  res += xpv;
  res = res > 0.f ? res : 0.f;
  if (wvalid) sm.h[t & (kHD - 1)][hwr] = res;
}

// fc for h[u] (ring slot u&15): same split-K-4 shape, global store.
__device__ __forceinline__ void fc_step(Smem& sm, int u, const float (&w)[4][32],
                                        int k, int rowk, float bfc,
                                        float* __restrict__ ob) {
  const float4* hp4 = (const float4*)sm.h[u & (kHD - 1)];
  float4 hc[8];
#pragma unroll
  for (int i = 0; i < 8; ++i) hc[i] = hp4[9 * k + i];
  float res = 0.f;
#pragma unroll
  for (int p = 0; p < 4; ++p) {
    float s0 = 0.f, s1 = 0.f, s2 = 0.f, s3 = 0.f;
#pragma unroll
    for (int i = 0; i < 8; ++i) {
      const float4 v = hc[i];
      s0 = fmaf(w[p][4 * i + 0], v.x, s0);
      s1 = fmaf(w[p][4 * i + 1], v.y, s1);
      s2 = fmaf(w[p][4 * i + 2], v.z, s2);
      s3 = fmaf(w[p][4 * i + 3], v.w, s3);
    }
    float c = (s0 + s1) + (s2 + s3);
    c = qadd2(qadd1(c));
    res = (k == p) ? c : res;
  }
  res += bfc;
  if (rowk < kO) ob[(size_t)u * kO + rowk] = res;
}

__device__ __forceinline__ void xp_step(Smem& sm, int xs, int slot,
                                        const float (&wi0)[kI],
                                        const float (&wi1)[kI],
                                        float bias0, float bias1, int ln) {
  const float4* xq = (const float4*)sm.xr[xs];
  float s00 = 0.f, s01 = 0.f, s02 = 0.f, s03 = 0.f;
  float s10 = 0.f, s11 = 0.f, s12 = 0.f, s13 = 0.f;
#pragma unroll
  for (int i = 0; i < 12; ++i) {
    float4 v = xq[i];
    s00 = fmaf(wi0[4 * i + 0], v.x, s00);
    s01 = fmaf(wi0[4 * i + 1], v.y, s01);
    s02 = fmaf(wi0[4 * i + 2], v.z, s02);
    s03 = fmaf(wi0[4 * i + 3], v.w, s03);
    s10 = fmaf(wi1[4 * i + 0], v.x, s10);
    s11 = fmaf(wi1[4 * i + 1], v.y, s11);
    s12 = fmaf(wi1[4 * i + 2], v.z, s12);
    s13 = fmaf(wi1[4 * i + 3], v.w, s13);
  }
  float2 vt = ((const float2*)sm.xr[xs])[24];  // elements 48,49
  s00 = fmaf(wi0[48], vt.x, s00);
  s01 = fmaf(wi0[49], vt.y, s01);
  s10 = fmaf(wi1[48], vt.x, s10);
  s11 = fmaf(wi1[49], vt.y, s11);
  sm.xp[slot][ln] = bias0 + ((s00 + s01) + (s02 + s03));
  if (ln < kH - 64) sm.xp[slot][ln + 64] = bias1 + ((s10 + s11) + (s12 + s13));
}

__launch_bounds__(256, 1)
__global__ void rnn_fused(const float* __restrict__ x,
                          const float* __restrict__ W_ih,
                          const float* __restrict__ b_ih,
                          const float* __restrict__ W_hh,
                          const float* __restrict__ b_hh,
                          const float* __restrict__ W_fc,
                          const float* __restrict__ b_fc,
                          float* __restrict__ out) {
  __shared__ Smem sm;
  const int tid = threadIdx.x;
  const int wv = tid >> 6;
  const int ln = tid & 63;
  const int b = blockIdx.x;
  const float* xb = x + (size_t)b * (kT * kI);
  float* ob = out + (size_t)b * (kT * kO);

  float w[4][32];          // waves 0-2: per-lane weight tile (chunk k, 4 rows)
  float wi0[kI], wi1[kI];  // wave 3: W_ih rows ln, ln+64
  float bias0 = 0.f, bias1 = 0.f, bfc = 0.f;
  float xrv[4] = {0.f, 0.f, 0.f, 0.f};  // x prefetch regs, xrv[q] -> ring slot q

  const int k = ln & 3;    // K-chunk (h columns [32k, 32k+32))
  const int rl = ln >> 2;  // local row 0..15
  int rowk = 0, hwr = 0;   // kept row after quad reduce; padded write index
  bool wvalid = false;

  if (wv < 2) {
    const int rbase = 58 * wv;
    rowk = rbase + rl + 16 * k;
    wvalid = (rl + 16 * k) < 58;
    hwr = 36 * (rowk >> 5) + (rowk & 31);
#pragma unroll
    for (int p = 0; p < 4; ++p) {
      const int rloc = rl + 16 * p;
      const bool vr = rloc < 58;
      const size_t r = rbase + (vr ? rloc : 0);
#pragma unroll
      for (int j = 0; j < 32; ++j) {
        const int col = 32 * k + j;
        w[p][j] = (vr && col < kH) ? W_hh[r * kH + col] : 0.f;
      }
    }
  } else if (wv == 2) {
    rowk = rl + 16 * k;
#pragma unroll
    for (int p = 0; p < 4; ++p) {
      const int rloc = rl + 16 * p;
      const bool vr = rloc < kO;
      const size_t r = vr ? rloc : 0;
#pragma unroll
      for (int j = 0; j < 32; ++j) {
        const int col = 32 * k + j;
        w[p][j] = (vr && col < kH) ? W_fc[r * kH + col] : 0.f;
      }
    }
    bfc = (rowk < kO) ? b_fc[rowk] : 0.f;
  } else {
    {
      const float2* wr = (const float2*)(W_ih + ln * kI);  // 200B rows: 8B aligned
#pragma unroll
      for (int i = 0; i < kI / 2; ++i) {
        float2 v = wr[i]; wi0[2 * i] = v.x; wi0[2 * i + 1] = v.y;
      }
      bias0 = b_ih[ln] + b_hh[ln];
    }
    if (ln < kH - 64) {
      const float2* wr = (const float2*)(W_ih + (ln + 64) * kI);
#pragma unroll
      for (int i = 0; i < kI / 2; ++i) {
        float2 v = wr[i]; wi1[2 * i] = v.x; wi1[2 * i + 1] = v.y;
      }
      bias1 = b_ih[ln + 64] + b_hh[ln + 64];
    } else {
#pragma unroll
      for (int i = 0; i < kI; ++i) wi1[i] = 0.f;
    }
    if (ln < kI) {
      // Ring invariant at step tau: slots tau&3, (tau+1)&3 hold x[tau],
      // x[tau+1]; xrv[q] holds the x destined for slot q.
      sm.xr[0][ln] = xb[0 * kI + ln];
      sm.xr[1][ln] = xb[1 * kI + ln];
      xrv[2] = xb[2 * kI + ln];
      xrv[3] = xb[3 * kI + ln];
      xrv[0] = xb[4 * kI + ln];
      xrv[1] = xb[5 * kI + ln];
    }
  }
  // h(-1) = 0 lives at slot (0-1)&15 = 15 (padded tail included).
  if (tid < 144) sm.h[kHD - 1][tid] = 0.f;
  if (tid == 0) { sm.flags[0] = -1; sm.flags[1] = -1; }
  sync_lds();  // barrier: init published

  if (wv < 2) __builtin_amdgcn_s_setprio(1);  // favor the recurrence waves

  // xp prologue: tau = 0..7 fills xp slots 0..7 so h can start at t=0.
  if (wv == 3) {
#pragma unroll
    for (int j = 0; j < kSS; ++j) {
      xp_step(sm, j & 3, j & (kXPD - 1), wi0, wi1, bias0, bias1, ln);
      if (ln < kI) {
        sm.xr[(j + 2) & 3][ln] = xrv[(j + 2) & 3];
        const int tf = j + 6;  // <= 13, no clamp needed
        xrv[(j + 2) & 3] = xb[(size_t)tf * kI + ln];
      }
    }
  }
  sync_lds();  // barrier: xp[0..7] published

  volatile int* my = (volatile int*)&sm.flags[wv & 1];
  const volatile int* oth = (const volatile int*)&sm.flags[1 - (wv & 1)];

#pragma unroll 1
  for (int s = 0; s < kT / kSS; ++s) {
    if (wv < 2) {
      // 8 serial steps; pairwise flag handshake instead of a full barrier.
      // Poll guarantees skew <= 1 step between the two h-waves.
      const int t0 = kSS * s;
#pragma unroll
      for (int j = 0; j < kSS; ++j) {
        const int t = t0 + j;
        if (j > 0) wait_flag(oth, t - 1);  // j==0: published by the barrier
        h_step(sm, t, w, k, rowk, hwr, wvalid);
        __asm__ __volatile__("" ::: "memory");  // keep h-writes before flag
        if (ln == 0) *my = t;
      }
    } else if (wv == 2) {
      // Lag one superstep: u in [8s-8, 8s-1]; all h[u] barrier-published.
      if (s > 0) {
        const int u0 = kSS * (s - 1);
#pragma unroll
        for (int j = 0; j < kSS; ++j)
          fc_step(sm, u0 + j, w, k, rowk, bfc, ob);
      }
    } else {
      // Lead one superstep: tau in [8s+8, 8s+15]; slots disjoint (mod 16)
      // from the h-waves' reads this superstep.
      if (s < kT / kSS - 1) {
        const int tau0 = kSS * s + kSS;
#pragma unroll
        for (int j = 0; j < kSS; ++j) {
          const int tau = tau0 + j;
          xp_step(sm, j & 3, tau & (kXPD - 1), wi0, wi1, bias0, bias1, ln);
          if (ln < kI) {
            sm.xr[(j + 2) & 3][ln] = xrv[(j + 2) & 3];  // (tau+2)&3 == (j+2)&3
            int tf = tau + 6; tf = tf < kT ? tf : kT - 1;
            xrv[(j + 2) & 3] = xb[(size_t)tf * kI + ln];
          }
        }
      }
    }
    sync_lds();  // one barrier per 8 steps
  }

  // fc epilogue: u = 2040..2047 (published by the final barrier).
  if (wv == 2) {
#pragma unroll
    for (int j = 0; j < kSS; ++j)
      fc_step(sm, kT - kSS + j, w, k, rowk, bfc, ob);
  }
}

extern "C" void kernel_launch(void* const* d_in, const int* in_sizes, int n_in,
                              void* d_out, int out_size, void* d_ws, size_t ws_size,
                              hipStream_t stream) {
  (void)in_sizes; (void)n_in; (void)d_ws; (void)ws_size; (void)out_size;
  const float* x    = (const float*)d_in[0];
  const float* W_ih = (const float*)d_in[1];
  const float* b_ih = (const float*)d_in[2];
  const float* W_hh = (const float*)d_in[3];
  const float* b_hh = (const float*)d_in[4];
  const float* W_fc = (const float*)d_in[5];
  const float* b_fc = (const float*)d_in[6];
  float* out = (float*)d_out;
  rnn_fused<<<dim3(kB), dim3(256), 0, stream>>>(x, W_ih, b_ih, W_hh, b_hh,
                                                W_fc, b_fc, out);
}